// Round 8
// baseline (623.762 us; speedup 1.0000x reference)
//
#include <hip/hip_runtime.h>

#define DIMV 3
#define RV 3
#define CV 32
#define ROWF 67
#define ROWO 35
#define CAP 48          // per-node edge slots in LDS; max deg ~40, +margin
#define PADSTR 49       // ue row stride in float4 (odd -> spreads bank groups)
#define SCAN_T 1024
#define BSH 5           // 32-node buckets
#define BNODES 32
// coarse split geometry
#define PART_SH 10      // 1024 nodes per partition
#define MAXP 128        // supports N < 2^17
#define RING 64         // LDS ring slots per partition
#define PSEG 24576      // records per partition segment (mean 16.4K + pad, +40 sigma)
#define CB_BLOCKS 256
#define CB_THREADS 1024
#define INVALID_REC 0xFFFFFFFFu

__device__ __forceinline__ float fast_tanh(float x) {
    float ex = __expf(2.0f * x);
    return (ex - 1.0f) * __builtin_amdgcn_rcpf(ex + 1.0f);
}

// ---------- shared prep: nd[n]={x,y,z,hsum}; zero counts+partition cursors; out coords ----------
__global__ void prep_kernel(const float* __restrict__ features,
                            float4* __restrict__ nd,
                            int* __restrict__ counts,
                            int* __restrict__ bcur, int nbc,
                            float* __restrict__ out, int N) {
    int gid = blockIdx.x * blockDim.x + threadIdx.x;
    if (gid < N) counts[gid] = 0;
    if (gid < nbc) bcur[gid] = 0;
    int node = gid >> 6;
    int lane = threadIdx.x & 63;
    if (node >= N) return;
    const float* row = features + (size_t)node * ROWF;
    float f0 = row[lane];                                    // 0..63
    float f1 = (lane < ROWF - 64) ? row[64 + lane] : 0.0f;   // 64..66
    float v = (lane >= DIMV ? f0 : 0.0f) + f1;               // h = 3..66
    for (int off = 32; off > 0; off >>= 1) v += __shfl_xor(v, off, 64);
    float c0 = __shfl(f0, 0, 64);
    float c1 = __shfl(f0, 1, 64);
    float c2 = __shfl(f0, 2, 64);
    if (lane == 0) nd[node] = make_float4(c0, c1, c2, v);
    if (lane < DIMV) out[(size_t)node * ROWO + lane] = f0;
}

// ---------- phase 1: LDS-staged coarse split, full-line coalesced writes ONLY ----------
// Empirical law (R0/R1/R2/R4/R7): L2/MALL never merges scattered sub-line global
// stores on this part; the only merge path is same-instruction wave coalescing.
// So: per-partition 64-slot LDS ring; waves flush full 16-record lines with a
// single 64-lane contiguous dword store (up to 4 lines = 256B per instruction).
// Record: srcLocal(10b)<<17 | dst(17b). Residual lines padded with INVALID_REC.
__global__ __launch_bounds__(CB_THREADS, 1)
void coarse_bin_kernel(const int2* __restrict__ ei2,
                       int* __restrict__ gcur,
                       unsigned int* __restrict__ bins, int E, int P) {
    __shared__ unsigned int ring[MAXP][RING];   // 32 KB
    __shared__ int cnt[MAXP];
    __shared__ int flushed[MAXP];               // in units of 16-record lines
    int t = threadIdx.x;
    for (int i = t; i < P; i += CB_THREADS) { cnt[i] = 0; flushed[i] = 0; }
    __syncthreads();
    long long e0 = (long long)E * blockIdx.x / CB_BLOCKS;
    long long e1 = (long long)E * (blockIdx.x + 1) / CB_BLOCKS;
    int wv = t >> 6, lane = t & 63;
    for (long long cs = e0; cs < e1; cs += 2 * CB_THREADS) {
#pragma unroll
        for (int j = 0; j < 2; ++j) {
            long long e = cs + (long long)j * CB_THREADS + t;
            if (e < e1) {
                unsigned long long v =
                    __builtin_nontemporal_load((const unsigned long long*)ei2 + e);
                int s = (int)(v & 0xffffffffull);
                int d = (int)(v >> 32);
                int p = s >> PART_SH;
                int slot = atomicAdd(&cnt[p], 1);
                ring[p][slot & (RING - 1)] =
                    ((unsigned)(s & ((1 << PART_SH) - 1)) << 17) | (unsigned)d;
            }
        }
        __syncthreads();
        // sweep: wave wv owns partitions wv, wv+16, ...
        for (int p2 = wv; p2 < P; p2 += CB_THREADS / 64) {
            int c = cnt[p2];
            int fl = flushed[p2];
            int pend = (c >> 4) - fl;
            while (pend > 0) {
                int L = pend > 4 ? 4 : pend;
                int gpos = 0;
                if (lane == 0) gpos = atomicAdd(&gcur[p2], L << 4);
                gpos = __shfl(gpos, 0, 64);
                if (lane < (L << 4) && gpos + (L << 4) <= PSEG)
                    bins[(size_t)p2 * PSEG + gpos + lane] =
                        ring[p2][((fl << 4) + lane) & (RING - 1)];
                fl += L;
                pend -= L;
            }
            if (lane == 0) flushed[p2] = fl;
        }
        __syncthreads();
    }
    // final residual: pad to a full line with INVALID (self-skipping in filter)
    for (int p2 = wv; p2 < P; p2 += CB_THREADS / 64) {
        int c = cnt[p2];
        int fl = flushed[p2];
        int rem = c - (fl << 4);
        if (rem > 0) {
            int gpos = 0;
            if (lane == 0) gpos = atomicAdd(&gcur[p2], 16);
            gpos = __shfl(gpos, 0, 64);
            if (lane < 16 && gpos + 16 <= PSEG) {
                unsigned r = (lane < rem)
                    ? ring[p2][((fl << 4) + lane) & (RING - 1)] : INVALID_REC;
                bins[(size_t)p2 * PSEG + gpos + lane] = r;
            }
        }
    }
}

// ---------- phase 2: fused 32-node bucket kernel, barrier-free compute ----------
// Input = parent partition's record list (32 buckets/partition), filtered by
// the 5 bucket bits (r>>22). INVALID pads give r>>22=1023 -> auto-skipped.
// Partition list (~74KB) is read by its 32 sibling blocks -> L2/MALL-served.
__global__ __launch_bounds__(256, 6)
void fused_bucket_kernel(const int* __restrict__ gcur,
                         const unsigned int* __restrict__ bins,
                         const float4* __restrict__ nd,
                         const float* __restrict__ wd,
                         const float* __restrict__ bd,
                         const float* __restrict__ mu,
                         const float* __restrict__ sig,
                         float* __restrict__ out, int N) {
    __shared__ float4 ue[BNODES * PADSTR];     // 25.1 KB
    __shared__ float4 snd[BNODES];
    __shared__ int lcnt[BNODES];
    int b = blockIdx.x;
    int base = b << BSH;
    int nn = N - base; if (nn > BNODES) nn = BNODES;
    int t = threadIdx.x;
    int p   = b >> (PART_SH - BSH);            // parent partition
    int grp = b & ((1 << (PART_SH - BSH)) - 1);// bucket-within-partition (5b)
    if (t < BNODES) {
        lcnt[t] = 0;
        snd[t] = (t < nn) ? nd[base + t] : make_float4(0.f, 0.f, 0.f, 0.f);
    }
    __syncthreads();
    {
        float w0 = wd[0], w1 = wd[1], w2 = wd[2];
        float w3 = wd[3], w4 = wd[4], w5 = wd[5];
        float w6 = wd[6], w7 = wd[7], w8 = wd[8];
        float b0 = bd[0], b1 = bd[1], b2 = bd[2];
        int total = gcur[p];
        if (total > PSEG) total = PSEG;
        total &= ~15;                          // always multiple of 16 anyway
        const uint4* rp = (const uint4*)(bins + (size_t)p * PSEG);
        int n4 = total >> 2;
        for (int i = t; i < n4; i += 256) {
            uint4 q4 = rp[i];
            unsigned rr[4] = {q4.x, q4.y, q4.z, q4.w};
#pragma unroll
            for (int jj = 0; jj < 4; ++jj) {
                unsigned r = rr[jj];
                if ((r >> 22) == (unsigned)grp) {   // INVALID -> 1023, skipped
                    int sl = (r >> 17) & (BNODES - 1);
                    int d  = r & 0x1FFFF;
                    float4 pd = nd[d];         // random gather, 1.6MB L2-resident
                    int k = atomicAdd(&lcnt[sl], 1);
                    if (k >= CAP) k = CAP - 1; // never expected; OOB guard only
                    float4 ps = snd[sl];
                    float dx = pd.x - ps.x, dy = pd.y - ps.y, dz = pd.z - ps.z;
                    float u0 = fast_tanh(dx * w0 + dy * w3 + dz * w6 + b0);
                    float u1 = fast_tanh(dx * w1 + dy * w4 + dz * w7 + b1);
                    float u2 = fast_tanh(dx * w2 + dy * w5 + dz * w8 + b2);
                    // column swizzle de-aliases the 4-way bank groups below
                    ue[sl * PADSTR + (k ^ ((sl >> 3) & 3))] =
                        make_float4(u0, u1, u2, pd.w);
                }
            }
        }
    }
    __syncthreads();
    // ---- barrier-free compute: lane (wv,h,n) owns clusters {8wv+2j+h} ----
    int wv = t >> 6;
    int l  = t & 63;
    int h  = l >> 5;
    int n  = l & 31;
    size_t slab = (size_t)N * RV;
    int nid = base + ((n < nn) ? n : 0);
    float3 mv[4], sv[4];
#pragma unroll
    for (int j = 0; j < 4; ++j) {
        int c = 8 * wv + 2 * j + h;
        const float* mp = mu  + (size_t)c * slab + (size_t)nid * RV;
        const float* sp = sig + (size_t)c * slab + (size_t)nid * RV;
        mv[j] = *(const float3*)mp;            // dwordx3, dense 2x384B/instr
        sv[j] = *(const float3*)sp;
    }
    float mm[4][3], im[4][3], acc[4];
#pragma unroll
    for (int j = 0; j < 4; ++j) {
        mm[j][0] = mv[j].x; mm[j][1] = mv[j].y; mm[j][2] = mv[j].z;
        im[j][0] = __builtin_amdgcn_rcpf(sv[j].x);
        im[j][1] = __builtin_amdgcn_rcpf(sv[j].y);
        im[j][2] = __builtin_amdgcn_rcpf(sv[j].z);
        acc[j] = 0.0f;
    }
    int cnt = (n < nn) ? min(lcnt[n], CAP) : 0;
    int key = (n >> 3) & 3;
    for (int k = 0; k < cnt; ++k) {
        float4 q = ue[n * PADSTR + (k ^ key)];
#pragma unroll
        for (int j = 0; j < 4; ++j) {
            float d0 = q.x - mm[j][0], d1 = q.y - mm[j][1], d2 = q.z - mm[j][2];
            float t2 = d0 * d0 * im[j][0] + d1 * d1 * im[j][1] + d2 * d2 * im[j][2];
            acc[j] += __expf(-0.5f * t2) * q.w;
        }
    }
    if (n < nn) {
        float* orow = out + (size_t)(base + n) * ROWO + DIMV;
#pragma unroll
        for (int j = 0; j < 4; ++j) orow[8 * wv + 2 * j + h] = acc[j];
    }
}

// ---------- full path (exact CSR + scan), ws fallback ----------

__global__ void hist_kernel(const int2* __restrict__ ei2, int* __restrict__ counts, int E) {
    int e = blockIdx.x * blockDim.x + threadIdx.x;
    if (e >= E) return;
    atomicAdd(counts + ei2[e].x, 1);
}

__global__ void scan_a_kernel(const int* __restrict__ counts, int* __restrict__ offsets,
                              int* __restrict__ partials, int N) {
    __shared__ int sm[SCAN_T];
    int t = threadIdx.x;
    int i = blockIdx.x * SCAN_T + t;
    int c = (i < N) ? counts[i] : 0;
    sm[t] = c;
    __syncthreads();
    for (int off = 1; off < SCAN_T; off <<= 1) {
        int v = (t >= off) ? sm[t - off] : 0;
        __syncthreads();
        sm[t] += v;
        __syncthreads();
    }
    if (i < N) offsets[i] = sm[t] - c;
    if (t == SCAN_T - 1) partials[blockIdx.x] = sm[t];
}

__global__ void scan_b_kernel(int* __restrict__ partials, int B) {
    __shared__ int sm[SCAN_T];
    int t = threadIdx.x;
    int c = (t < B) ? partials[t] : 0;
    sm[t] = c;
    __syncthreads();
    for (int off = 1; off < SCAN_T; off <<= 1) {
        int v = (t >= off) ? sm[t - off] : 0;
        __syncthreads();
        sm[t] += v;
        __syncthreads();
    }
    if (t < B) partials[t] = sm[t] - c;
}

__global__ void scan_c_kernel(int* __restrict__ offsets, const int* __restrict__ partials,
                              int* __restrict__ cursor, int N, int E) {
    int i = blockIdx.x * blockDim.x + threadIdx.x;
    if (i == 0) offsets[N] = E;
    if (i >= N) return;
    int off = offsets[i] + partials[i / SCAN_T];
    offsets[i] = off;
    cursor[i] = off;
}

__global__ void scatter_u_kernel(const int2* __restrict__ ei2, int* __restrict__ cursor,
                                 const float4* __restrict__ nd,
                                 const float* __restrict__ wd, const float* __restrict__ bd,
                                 float4* __restrict__ ue, int E) {
    int e = blockIdx.x * blockDim.x + threadIdx.x;
    if (e >= E) return;
    int2 sd = ei2[e];
    int pos = atomicAdd(cursor + sd.x, 1);
    float4 ps = nd[sd.x];
    float4 pd = nd[sd.y];
    float dx = pd.x - ps.x, dy = pd.y - ps.y, dz = pd.z - ps.z;
    float u0 = fast_tanh(dx * wd[0] + dy * wd[3] + dz * wd[6] + bd[0]);
    float u1 = fast_tanh(dx * wd[1] + dy * wd[4] + dz * wd[7] + bd[1]);
    float u2 = fast_tanh(dx * wd[2] + dy * wd[5] + dz * wd[8] + bd[2]);
    ue[pos] = make_float4(u0, u1, u2, pd.w);
}

__global__ void node_acc2_kernel(const int* __restrict__ offsets,
                                 const float4* __restrict__ ue,
                                 const float* __restrict__ mu,
                                 const float* __restrict__ sig,
                                 float* __restrict__ out, int N) {
    int node = (blockIdx.x * blockDim.x + threadIdx.x) >> 6;
    if (node >= N) return;
    int lane = threadIdx.x & 63;
    int c = lane & 31;
    int half = lane >> 5;
    size_t slab = (size_t)N * RV;
    const float* mp = mu + (size_t)c * slab + (size_t)node * RV;
    const float* sp = sig + (size_t)c * slab + (size_t)node * RV;
    float m0 = mp[0], m1 = mp[1], m2 = mp[2];
    float i0 = __builtin_amdgcn_rcpf(sp[0]);
    float i1 = __builtin_amdgcn_rcpf(sp[1]);
    float i2 = __builtin_amdgcn_rcpf(sp[2]);
    int off0 = offsets[node], off1 = offsets[node + 1];
    float acc = 0.0f;
    for (int i = off0 + half; i < off1; i += 2) {
        float4 q = ue[i];
        float d0 = q.x - m0, d1 = q.y - m1, d2 = q.z - m2;
        float t = d0 * d0 * i0 + d1 * d1 * i1 + d2 * d2 * i2;
        acc += __expf(-0.5f * t) * q.w;
    }
    acc += __shfl_xor(acc, 32, 64);
    if (half == 0) out[(size_t)node * ROWO + DIMV + c] = acc;
}

// ---------- last-resort path (edge-atomic) ----------

__global__ void fb_pre_kernel(const float* __restrict__ features,
                              float4* __restrict__ nd, float* __restrict__ out, int N) {
    int gid = blockIdx.x * blockDim.x + threadIdx.x;
    int node = gid >> 6;
    int lane = threadIdx.x & 63;
    if (node >= N) return;
    const float* row = features + (size_t)node * ROWF;
    float f0 = row[lane];
    float f1 = (lane < ROWF - 64) ? row[64 + lane] : 0.0f;
    float v = (lane >= DIMV ? f0 : 0.0f) + f1;
    for (int off = 32; off > 0; off >>= 1) v += __shfl_xor(v, off, 64);
    float c0 = __shfl(f0, 0, 64);
    float c1 = __shfl(f0, 1, 64);
    float c2 = __shfl(f0, 2, 64);
    if (lane == 0) nd[node] = make_float4(c0, c1, c2, v);
    float* orow = out + (size_t)node * ROWO;
    if (lane < DIMV) orow[lane] = f0;
    else if (lane < ROWO) orow[lane] = 0.0f;
}

__global__ void fb_edge_kernel(const int* __restrict__ ei, const float4* __restrict__ nd,
                               const float* __restrict__ wd, const float* __restrict__ bd,
                               const float* __restrict__ mu, const float* __restrict__ sig,
                               float* __restrict__ out, int N, int E) {
    int e = blockIdx.x * blockDim.x + threadIdx.x;
    if (e >= E) return;
    int s = ei[2 * e];
    int d = ei[2 * e + 1];
    float4 ps = nd[s];
    float4 pd = nd[d];
    float dx = pd.x - ps.x, dy = pd.y - ps.y, dz = pd.z - ps.z;
    float u0 = fast_tanh(dx * wd[0] + dy * wd[3] + dz * wd[6] + bd[0]);
    float u1 = fast_tanh(dx * wd[1] + dy * wd[4] + dz * wd[7] + bd[1]);
    float u2 = fast_tanh(dx * wd[2] + dy * wd[5] + dz * wd[8] + bd[2]);
    float hs = pd.w;
    float* oagg = out + (size_t)s * ROWO + DIMV;
    size_t nodeoff = (size_t)s * RV;
    size_t slab = (size_t)N * RV;
#pragma unroll 4
    for (int c = 0; c < CV; ++c) {
        const float* mp = mu + (size_t)c * slab + nodeoff;
        const float* sp = sig + (size_t)c * slab + nodeoff;
        float d0 = u0 - mp[0], d1 = u1 - mp[1], d2 = u2 - mp[2];
        float t = d0 * d0 * __builtin_amdgcn_rcpf(sp[0])
                + d1 * d1 * __builtin_amdgcn_rcpf(sp[1])
                + d2 * d2 * __builtin_amdgcn_rcpf(sp[2]);
        atomicAdd(oagg + c, __expf(-0.5f * t) * hs);
    }
}

extern "C" void kernel_launch(void* const* d_in, const int* in_sizes, int n_in,
                              void* d_out, int out_size, void* d_ws, size_t ws_size,
                              hipStream_t stream) {
    const float* features = (const float*)d_in[0];
    const int*   ei       = (const int*)d_in[1];
    const int2*  ei2      = (const int2*)d_in[1];
    const float* wd       = (const float*)d_in[2];
    const float* bd       = (const float*)d_in[3];
    const float* mu       = (const float*)d_in[4];
    const float* sig      = (const float*)d_in[5];
    float* out = (float*)d_out;

    int N = in_sizes[0] / ROWF;
    int E = in_sizes[1] / 2;
    int B = (N + SCAN_T - 1) / SCAN_T;
    int NB = (N + BNODES - 1) / BNODES;          // fused blocks (32-node buckets)
    int P  = (N + (1 << PART_SH) - 1) >> PART_SH;// coarse partitions

    size_t cur = 0;
    auto take = [&](size_t bytes) { size_t p = cur; cur += (bytes + 255) & ~(size_t)255; return p; };
    size_t o_nd      = take((size_t)N * sizeof(float4));
    size_t o_counts  = take((size_t)N * sizeof(int));
    size_t o_offsets = take((size_t)(N + 1) * sizeof(int));
    size_t o_cursor  = take((size_t)N * sizeof(int));
    size_t o_part    = take((size_t)SCAN_T * sizeof(int));
    size_t o_gcur    = take((size_t)MAXP * sizeof(int));
    size_t o_bins    = take((size_t)MAXP * PSEG * sizeof(unsigned int));
    size_t o_tail    = cur;     // CSR ue only
    size_t need_fused = o_tail; // fused path needs nothing past bins
    size_t need_full  = o_tail + (((size_t)E * sizeof(float4) + 255) & ~(size_t)255);

    char* ws = (char*)d_ws;
    float4* nd   = (float4*)(ws + o_nd);
    int* counts  = (int*)(ws + o_counts);
    int* offsets = (int*)(ws + o_offsets);
    int* cursor  = (int*)(ws + o_cursor);
    int* part    = (int*)(ws + o_part);
    int* gcur    = (int*)(ws + o_gcur);
    unsigned int* bins = (unsigned int*)(ws + o_bins);

    if (ws_size >= need_fused && N < (1 << 17)) {
        // 3-kernel path: prep -> LDS-staged coarse split -> fused buckets
        prep_kernel<<<(N + 3) / 4, 256, 0, stream>>>(features, nd, counts, gcur, MAXP, out, N);
        coarse_bin_kernel<<<CB_BLOCKS, CB_THREADS, 0, stream>>>(ei2, gcur, bins, E, P);
        fused_bucket_kernel<<<NB, 256, 0, stream>>>(gcur, bins, nd, wd, bd, mu, sig, out, N);
    } else if (ws_size >= need_full && B <= SCAN_T) {
        float4* ue = (float4*)(ws + o_tail);
        prep_kernel<<<(N + 3) / 4, 256, 0, stream>>>(features, nd, counts, gcur, 0, out, N);
        hist_kernel<<<(E + 255) / 256, 256, 0, stream>>>(ei2, counts, E);
        scan_a_kernel<<<B, SCAN_T, 0, stream>>>(counts, offsets, part, N);
        scan_b_kernel<<<1, SCAN_T, 0, stream>>>(part, B);
        scan_c_kernel<<<(N + 255) / 256, 256, 0, stream>>>(offsets, part, cursor, N, E);
        scatter_u_kernel<<<(E + 255) / 256, 256, 0, stream>>>(ei2, cursor, nd, wd, bd, ue, E);
        node_acc2_kernel<<<(N + 3) / 4, 256, 0, stream>>>(offsets, ue, mu, sig, out, N);
    } else {
        fb_pre_kernel<<<(N + 3) / 4, 256, 0, stream>>>(features, nd, out, N);
        fb_edge_kernel<<<(E + 255) / 256, 256, 0, stream>>>(ei, nd, wd, bd, mu, sig, out, N, E);
    }
}

// Round 9
// 252.561 us; speedup vs baseline: 2.4697x; 2.4697x over previous
//
#include <hip/hip_runtime.h>

#define DIMV 3
#define RV 3
#define CV 32
#define ROWF 67
#define ROWO 35
#define CAP 48          // per-node edge slots in LDS; max deg ~40, +margin
#define PADSTR 49       // ue row stride in float4 (odd -> spreads bank groups)
#define SCAN_T 1024
#define NGRP 8          // physical XCDs
#define BSH 5           // 32-node buckets
#define BNODES 32
#define SEGCAP 192      // per-(xcd,bucket) capacity; mean 64; redirect on overflow

__device__ __forceinline__ float fast_tanh(float x) {
    float ex = __expf(2.0f * x);
    return (ex - 1.0f) * __builtin_amdgcn_rcpf(ex + 1.0f);
}

// physical XCD id (0..7), wave-uniform — verified on gfx950 (learn_hip m09)
__device__ __forceinline__ int xcc_id() {
    int x;
    asm("s_getreg_b32 %0, hwreg(HW_REG_XCC_ID)" : "=s"(x));
    return x & (NGRP - 1);
}

// ---------- shared prep: nd[n]={x,y,z,hsum}; zero counts+bin cursors; out coords ----------
__global__ void prep_kernel(const float* __restrict__ features,
                            float4* __restrict__ nd,
                            int* __restrict__ counts,
                            int* __restrict__ bcur, int nbc,
                            float* __restrict__ out, int N) {
    int gid = blockIdx.x * blockDim.x + threadIdx.x;
    if (gid < N) counts[gid] = 0;
    if (gid < nbc) bcur[gid] = 0;
    int node = gid >> 6;
    int lane = threadIdx.x & 63;
    if (node >= N) return;
    const float* row = features + (size_t)node * ROWF;
    float f0 = __builtin_nontemporal_load(row + lane);       // 0..63, streamed once
    float f1 = (lane < ROWF - 64)
             ? __builtin_nontemporal_load(row + 64 + lane) : 0.0f; // 64..66
    float v = (lane >= DIMV ? f0 : 0.0f) + f1;               // h = 3..66
    for (int off = 32; off > 0; off >>= 1) v += __shfl_xor(v, off, 64);
    float c0 = __shfl(f0, 0, 64);
    float c1 = __shfl(f0, 1, 64);
    float c2 = __shfl(f0, 2, 64);
    if (lane == 0) nd[node] = make_float4(c0, c1, c2, v);
    if (lane < DIMV) out[(size_t)node * ROWO + lane] = f0;
}

// ---------- phase 1: bin edges into per-(PHYSICAL-XCD, bucket) segments, 4B records ----------
// group = hardware XCC_ID -> each segment tail line dirtied by exactly one L2.
// Overflow redirects to the next group. Record: srcLocal(5b)<<17 | dst(17b).
// Cost model (verified R7): 2 L2 transactions/edge x ~14cyc = ~73us floor.
__global__ void bin_kernel(const int2* __restrict__ ei2,
                           int* __restrict__ bcur,
                           unsigned int* __restrict__ bins, int E, int NB) {
    int grp = xcc_id();
    int stride = gridDim.x * blockDim.x;
    for (int e = blockIdx.x * blockDim.x + threadIdx.x; e < E; e += stride) {
        unsigned long long v =
            __builtin_nontemporal_load((const unsigned long long*)ei2 + e);
        int s = (int)(v & 0xffffffffull);
        int d = (int)(v >> 32);
        int b = s >> BSH;
        int g = grp;
        int slot = atomicAdd(bcur + g * NB + b, 1);
#pragma unroll 1
        for (int tries = 0; slot >= SEGCAP && tries < NGRP; ++tries) {
            g = (g + 1) & (NGRP - 1);
            slot = atomicAdd(bcur + g * NB + b, 1);
        }
        if (slot < SEGCAP)
            bins[(size_t)(g * NB + b) * SEGCAP + slot] =
                ((unsigned)(s & (BNODES - 1)) << 17) | (unsigned)d;
    }
}

// ---------- phase 2: fused 32-node bucket kernel, barrier-free compute ----------
// Edge build into LDS (one barrier), then each lane owns 4 (cluster,node) pairs:
// mu/sig loaded DIRECTLY global->reg via dwordx3 (lanes (h,n) cover two dense
// 384B segments per instruction), one k-loop computes 4 clusters per ue read.
// No mu/sig LDS, no per-chunk barriers. ~25.8KB LDS -> 6 blocks/CU.
__global__ __launch_bounds__(256, 6)
void fused_bucket_kernel(const int* __restrict__ bcur,
                         const unsigned int* __restrict__ bins,
                         const float4* __restrict__ nd,
                         const float* __restrict__ wd,
                         const float* __restrict__ bd,
                         const float* __restrict__ mu,
                         const float* __restrict__ sig,
                         float* __restrict__ out, int N, int NB) {
    __shared__ float4 ue[BNODES * PADSTR];     // 25.1 KB
    __shared__ float4 snd[BNODES];             // 512 B
    __shared__ int lcnt[BNODES];               // 128 B
    __shared__ int soff[NGRP + 1];
    int b = blockIdx.x;
    int base = b << BSH;
    int nn = N - base; if (nn > BNODES) nn = BNODES;
    int t = threadIdx.x;
    if (t < BNODES) {
        lcnt[t] = 0;
        snd[t] = (t < nn) ? nd[base + t] : make_float4(0.f, 0.f, 0.f, 0.f);
    }
    if (t < NGRP) {
        int c = bcur[t * NB + b];
        soff[t + 1] = (c > SEGCAP) ? SEGCAP : c;
    }
    if (t == 0) soff[0] = 0;
    __syncthreads();
    if (t == 0) {
#pragma unroll
        for (int g = 0; g < NGRP; ++g) soff[g + 1] += soff[g];
    }
    __syncthreads();
    {
        float w0 = wd[0], w1 = wd[1], w2 = wd[2];
        float w3 = wd[3], w4 = wd[4], w5 = wd[5];
        float w6 = wd[6], w7 = wd[7], w8 = wd[8];
        float b0 = bd[0], b1 = bd[1], b2 = bd[2];
        int total = soff[NGRP];
        for (int r = t; r < total; r += 256) {
            int g = 0;
#pragma unroll
            for (int gg = 1; gg < NGRP; ++gg) if (r >= soff[gg]) g = gg;
            int i = r - soff[g];
            unsigned p = bins[(size_t)(g * NB + b) * SEGCAP + i];
            int sl = p >> 17;
            int d  = p & 0x1FFFF;
            float4 pd = nd[d];                 // random gather, 1.6MB L2-resident
            int k = atomicAdd(&lcnt[sl], 1);
            if (k >= CAP) k = CAP - 1;         // never expected; OOB guard only
            float4 ps = snd[sl];
            float dx = pd.x - ps.x, dy = pd.y - ps.y, dz = pd.z - ps.z;
            float u0 = fast_tanh(dx * w0 + dy * w3 + dz * w6 + b0);
            float u1 = fast_tanh(dx * w1 + dy * w4 + dz * w7 + b1);
            float u2 = fast_tanh(dx * w2 + dy * w5 + dz * w8 + b2);
            // column swizzle k^((sl>>3)&3): de-aliases the 4-way bank groups
            // of the 32-row read pattern below (stride 49*4 dwords ≡ 4 mod 32)
            ue[sl * PADSTR + (k ^ ((sl >> 3) & 3))] = make_float4(u0, u1, u2, pd.w);
        }
    }
    __syncthreads();
    // ---- barrier-free compute: lane (wv,h,n) owns clusters {8wv+2j+h} ----
    int wv = t >> 6;
    int l  = t & 63;
    int h  = l >> 5;
    int n  = l & 31;
    size_t slab = (size_t)N * RV;
    int nid = base + ((n < nn) ? n : 0);
    float3 mv[4], sv[4];
#pragma unroll
    for (int j = 0; j < 4; ++j) {
        int c = 8 * wv + 2 * j + h;
        const float* mp = mu  + (size_t)c * slab + (size_t)nid * RV;
        const float* sp = sig + (size_t)c * slab + (size_t)nid * RV;
        mv[j] = *(const float3*)mp;            // dwordx3, dense 2x384B/instr
        sv[j] = *(const float3*)sp;
    }
    float mm[4][3], im[4][3], acc[4];
#pragma unroll
    for (int j = 0; j < 4; ++j) {
        mm[j][0] = mv[j].x; mm[j][1] = mv[j].y; mm[j][2] = mv[j].z;
        im[j][0] = __builtin_amdgcn_rcpf(sv[j].x);
        im[j][1] = __builtin_amdgcn_rcpf(sv[j].y);
        im[j][2] = __builtin_amdgcn_rcpf(sv[j].z);
        acc[j] = 0.0f;
    }
    int cnt = (n < nn) ? min(lcnt[n], CAP) : 0;
    int key = (n >> 3) & 3;
    for (int k = 0; k < cnt; ++k) {
        float4 q = ue[n * PADSTR + (k ^ key)];
#pragma unroll
        for (int j = 0; j < 4; ++j) {
            float d0 = q.x - mm[j][0], d1 = q.y - mm[j][1], d2 = q.z - mm[j][2];
            float t2 = d0 * d0 * im[j][0] + d1 * d1 * im[j][1] + d2 * d2 * im[j][2];
            acc[j] += __expf(-0.5f * t2) * q.w;
        }
    }
    if (n < nn) {
        float* orow = out + (size_t)(base + n) * ROWO + DIMV;
#pragma unroll
        for (int j = 0; j < 4; ++j) orow[8 * wv + 2 * j + h] = acc[j];
    }
}

// ---------- full path (exact CSR + scan), ws fallback ----------

__global__ void hist_kernel(const int2* __restrict__ ei2, int* __restrict__ counts, int E) {
    int e = blockIdx.x * blockDim.x + threadIdx.x;
    if (e >= E) return;
    atomicAdd(counts + ei2[e].x, 1);
}

__global__ void scan_a_kernel(const int* __restrict__ counts, int* __restrict__ offsets,
                              int* __restrict__ partials, int N) {
    __shared__ int sm[SCAN_T];
    int t = threadIdx.x;
    int i = blockIdx.x * SCAN_T + t;
    int c = (i < N) ? counts[i] : 0;
    sm[t] = c;
    __syncthreads();
    for (int off = 1; off < SCAN_T; off <<= 1) {
        int v = (t >= off) ? sm[t - off] : 0;
        __syncthreads();
        sm[t] += v;
        __syncthreads();
    }
    if (i < N) offsets[i] = sm[t] - c;
    if (t == SCAN_T - 1) partials[blockIdx.x] = sm[t];
}

__global__ void scan_b_kernel(int* __restrict__ partials, int B) {
    __shared__ int sm[SCAN_T];
    int t = threadIdx.x;
    int c = (t < B) ? partials[t] : 0;
    sm[t] = c;
    __syncthreads();
    for (int off = 1; off < SCAN_T; off <<= 1) {
        int v = (t >= off) ? sm[t - off] : 0;
        __syncthreads();
        sm[t] += v;
        __syncthreads();
    }
    if (t < B) partials[t] = sm[t] - c;
}

__global__ void scan_c_kernel(int* __restrict__ offsets, const int* __restrict__ partials,
                              int* __restrict__ cursor, int N, int E) {
    int i = blockIdx.x * blockDim.x + threadIdx.x;
    if (i == 0) offsets[N] = E;
    if (i >= N) return;
    int off = offsets[i] + partials[i / SCAN_T];
    offsets[i] = off;
    cursor[i] = off;
}

__global__ void scatter_u_kernel(const int2* __restrict__ ei2, int* __restrict__ cursor,
                                 const float4* __restrict__ nd,
                                 const float* __restrict__ wd, const float* __restrict__ bd,
                                 float4* __restrict__ ue, int E) {
    int e = blockIdx.x * blockDim.x + threadIdx.x;
    if (e >= E) return;
    int2 sd = ei2[e];
    int pos = atomicAdd(cursor + sd.x, 1);
    float4 ps = nd[sd.x];
    float4 pd = nd[sd.y];
    float dx = pd.x - ps.x, dy = pd.y - ps.y, dz = pd.z - ps.z;
    float u0 = fast_tanh(dx * wd[0] + dy * wd[3] + dz * wd[6] + bd[0]);
    float u1 = fast_tanh(dx * wd[1] + dy * wd[4] + dz * wd[7] + bd[1]);
    float u2 = fast_tanh(dx * wd[2] + dy * wd[5] + dz * wd[8] + bd[2]);
    ue[pos] = make_float4(u0, u1, u2, pd.w);
}

__global__ void node_acc2_kernel(const int* __restrict__ offsets,
                                 const float4* __restrict__ ue,
                                 const float* __restrict__ mu,
                                 const float* __restrict__ sig,
                                 float* __restrict__ out, int N) {
    int node = (blockIdx.x * blockDim.x + threadIdx.x) >> 6;
    if (node >= N) return;
    int lane = threadIdx.x & 63;
    int c = lane & 31;
    int half = lane >> 5;
    size_t slab = (size_t)N * RV;
    const float* mp = mu + (size_t)c * slab + (size_t)node * RV;
    const float* sp = sig + (size_t)c * slab + (size_t)node * RV;
    float m0 = mp[0], m1 = mp[1], m2 = mp[2];
    float i0 = __builtin_amdgcn_rcpf(sp[0]);
    float i1 = __builtin_amdgcn_rcpf(sp[1]);
    float i2 = __builtin_amdgcn_rcpf(sp[2]);
    int off0 = offsets[node], off1 = offsets[node + 1];
    float acc = 0.0f;
    for (int i = off0 + half; i < off1; i += 2) {
        float4 q = ue[i];
        float d0 = q.x - m0, d1 = q.y - m1, d2 = q.z - m2;
        float t = d0 * d0 * i0 + d1 * d1 * i1 + d2 * d2 * i2;
        acc += __expf(-0.5f * t) * q.w;
    }
    acc += __shfl_xor(acc, 32, 64);
    if (half == 0) out[(size_t)node * ROWO + DIMV + c] = acc;
}

// ---------- last-resort path (edge-atomic) ----------

__global__ void fb_pre_kernel(const float* __restrict__ features,
                              float4* __restrict__ nd, float* __restrict__ out, int N) {
    int gid = blockIdx.x * blockDim.x + threadIdx.x;
    int node = gid >> 6;
    int lane = threadIdx.x & 63;
    if (node >= N) return;
    const float* row = features + (size_t)node * ROWF;
    float f0 = row[lane];
    float f1 = (lane < ROWF - 64) ? row[64 + lane] : 0.0f;
    float v = (lane >= DIMV ? f0 : 0.0f) + f1;
    for (int off = 32; off > 0; off >>= 1) v += __shfl_xor(v, off, 64);
    float c0 = __shfl(f0, 0, 64);
    float c1 = __shfl(f0, 1, 64);
    float c2 = __shfl(f0, 2, 64);
    if (lane == 0) nd[node] = make_float4(c0, c1, c2, v);
    float* orow = out + (size_t)node * ROWO;
    if (lane < DIMV) orow[lane] = f0;
    else if (lane < ROWO) orow[lane] = 0.0f;
}

__global__ void fb_edge_kernel(const int* __restrict__ ei, const float4* __restrict__ nd,
                               const float* __restrict__ wd, const float* __restrict__ bd,
                               const float* __restrict__ mu, const float* __restrict__ sig,
                               float* __restrict__ out, int N, int E) {
    int e = blockIdx.x * blockDim.x + threadIdx.x;
    if (e >= E) return;
    int s = ei[2 * e];
    int d = ei[2 * e + 1];
    float4 ps = nd[s];
    float4 pd = nd[d];
    float dx = pd.x - ps.x, dy = pd.y - ps.y, dz = pd.z - ps.z;
    float u0 = fast_tanh(dx * wd[0] + dy * wd[3] + dz * wd[6] + bd[0]);
    float u1 = fast_tanh(dx * wd[1] + dy * wd[4] + dz * wd[7] + bd[1]);
    float u2 = fast_tanh(dx * wd[2] + dy * wd[5] + dz * wd[8] + bd[2]);
    float hs = pd.w;
    float* oagg = out + (size_t)s * ROWO + DIMV;
    size_t nodeoff = (size_t)s * RV;
    size_t slab = (size_t)N * RV;
#pragma unroll 4
    for (int c = 0; c < CV; ++c) {
        const float* mp = mu + (size_t)c * slab + nodeoff;
        const float* sp = sig + (size_t)c * slab + nodeoff;
        float d0 = u0 - mp[0], d1 = u1 - mp[1], d2 = u2 - mp[2];
        float t = d0 * d0 * __builtin_amdgcn_rcpf(sp[0])
                + d1 * d1 * __builtin_amdgcn_rcpf(sp[1])
                + d2 * d2 * __builtin_amdgcn_rcpf(sp[2]);
        atomicAdd(oagg + c, __expf(-0.5f * t) * hs);
    }
}

extern "C" void kernel_launch(void* const* d_in, const int* in_sizes, int n_in,
                              void* d_out, int out_size, void* d_ws, size_t ws_size,
                              hipStream_t stream) {
    const float* features = (const float*)d_in[0];
    const int*   ei       = (const int*)d_in[1];
    const int2*  ei2      = (const int2*)d_in[1];
    const float* wd       = (const float*)d_in[2];
    const float* bd       = (const float*)d_in[3];
    const float* mu       = (const float*)d_in[4];
    const float* sig      = (const float*)d_in[5];
    float* out = (float*)d_out;

    int N = in_sizes[0] / ROWF;
    int E = in_sizes[1] / 2;
    int B = (N + SCAN_T - 1) / SCAN_T;
    int NB = (N + BNODES - 1) / BNODES;

    size_t cur = 0;
    auto take = [&](size_t bytes) { size_t p = cur; cur += (bytes + 255) & ~(size_t)255; return p; };
    size_t o_nd      = take((size_t)N * sizeof(float4));
    size_t o_counts  = take((size_t)N * sizeof(int));
    size_t o_offsets = take((size_t)(N + 1) * sizeof(int));
    size_t o_cursor  = take((size_t)N * sizeof(int));
    size_t o_part    = take((size_t)SCAN_T * sizeof(int));
    size_t o_bcur    = take((size_t)NGRP * NB * sizeof(int));
    size_t o_bins    = take((size_t)NGRP * NB * SEGCAP * sizeof(unsigned int));
    size_t o_tail    = cur;     // CSR ue only
    size_t need_fused = o_tail; // fused path needs nothing past bins
    size_t need_full  = o_tail + (((size_t)E * sizeof(float4) + 255) & ~(size_t)255);

    char* ws = (char*)d_ws;
    float4* nd   = (float4*)(ws + o_nd);
    int* counts  = (int*)(ws + o_counts);
    int* offsets = (int*)(ws + o_offsets);
    int* cursor  = (int*)(ws + o_cursor);
    int* part    = (int*)(ws + o_part);
    int* bcur    = (int*)(ws + o_bcur);
    unsigned int* bins = (unsigned int*)(ws + o_bins);

    if (ws_size >= need_fused && N < (1 << 17)) {
        // 3-kernel fused-bucket path (best verified: R7, 256.8us)
        prep_kernel<<<(N + 3) / 4, 256, 0, stream>>>(features, nd, counts, bcur, NGRP * NB, out, N);
        bin_kernel<<<2048, 256, 0, stream>>>(ei2, bcur, bins, E, NB);
        fused_bucket_kernel<<<NB, 256, 0, stream>>>(bcur, bins, nd, wd, bd, mu, sig, out, N, NB);
    } else if (ws_size >= need_full && B <= SCAN_T) {
        float4* ue = (float4*)(ws + o_tail);
        prep_kernel<<<(N + 3) / 4, 256, 0, stream>>>(features, nd, counts, bcur, 0, out, N);
        hist_kernel<<<(E + 255) / 256, 256, 0, stream>>>(ei2, counts, E);
        scan_a_kernel<<<B, SCAN_T, 0, stream>>>(counts, offsets, part, N);
        scan_b_kernel<<<1, SCAN_T, 0, stream>>>(part, B);
        scan_c_kernel<<<(N + 255) / 256, 256, 0, stream>>>(offsets, part, cursor, N, E);
        scatter_u_kernel<<<(E + 255) / 256, 256, 0, stream>>>(ei2, cursor, nd, wd, bd, ue, E);
        node_acc2_kernel<<<(N + 3) / 4, 256, 0, stream>>>(offsets, ue, mu, sig, out, N);
    } else {
        fb_pre_kernel<<<(N + 3) / 4, 256, 0, stream>>>(features, nd, out, N);
        fb_edge_kernel<<<(E + 255) / 256, 256, 0, stream>>>(ei, nd, wd, bd, mu, sig, out, N, E);
    }
}

// Round 10
// 248.696 us; speedup vs baseline: 2.5081x; 1.0155x over previous
//
#include <hip/hip_runtime.h>

#define DIMV 3
#define RV 3
#define CV 32
#define ROWF 67
#define ROWO 35
#define CAP 48          // per-node edge slots in LDS; max deg ~40, +margin
#define PADSTR 49       // ue row stride in float4 (odd -> spreads bank groups)
#define SCAN_T 1024
#define NGRP 8          // physical XCDs
#define BSH 5           // 32-node buckets
#define BNODES 32
#define SEGCAP 192      // per-(xcd,bucket) capacity; mean 64; redirect on overflow
#define BINB 1024       // persistent bin blocks in merged kernel (= half the wave slots)

__device__ __forceinline__ float fast_tanh(float x) {
    float ex = __expf(2.0f * x);
    return (ex - 1.0f) * __builtin_amdgcn_rcpf(ex + 1.0f);
}

// physical XCD id (0..7), wave-uniform — verified on gfx950 (learn_hip m09)
__device__ __forceinline__ int xcc_id() {
    int x;
    asm("s_getreg_b32 %0, hwreg(HW_REG_XCC_ID)" : "=s"(x));
    return x & (NGRP - 1);
}

// ---------- strict-order zeroing of bin cursors (before any bin atomics) ----------
__global__ void zero_kernel(int* __restrict__ p, int n) {
    int i = blockIdx.x * blockDim.x + threadIdx.x;
    if (i < n) p[i] = 0;
}

// ---------- MERGED prep ∥ bin: blocks [0,BINB) bin, rest prep ----------
// prep and bin are data-independent (bin: ei2+bcur -> bins; prep: features -> nd,out).
// BINB=1024 blocks = 4096 waves = half the chip's wave slots, so prep blocks
// co-reside and cycle while the persistent bin blocks run at the L2 transaction
// wall (44G trans/s aggregate; 262K threads x 1-2 outstanding >> the ~18K needed).
__global__ __launch_bounds__(256)
void prep_bin_kernel(const float* __restrict__ features,
                     float4* __restrict__ nd,
                     float* __restrict__ out,
                     const int2* __restrict__ ei2,
                     int* __restrict__ bcur,
                     unsigned int* __restrict__ bins,
                     int N, int E, int NB) {
    if (blockIdx.x < BINB) {
        // ---- bin part: per-(PHYSICAL-XCD, bucket) segments, 4B records ----
        // group = XCC_ID -> each segment tail line dirtied by exactly one L2.
        // Cost model (verified R7/R9): 2 L2 transactions/edge x ~14cyc = ~72us.
        int grp = xcc_id();
        int stride = BINB * 256;
        for (int e = blockIdx.x * 256 + threadIdx.x; e < E; e += stride) {
            unsigned long long v =
                __builtin_nontemporal_load((const unsigned long long*)ei2 + e);
            int s = (int)(v & 0xffffffffull);
            int d = (int)(v >> 32);
            int b = s >> BSH;
            int g = grp;
            int slot = atomicAdd(bcur + g * NB + b, 1);
#pragma unroll 1
            for (int tries = 0; slot >= SEGCAP && tries < NGRP; ++tries) {
                g = (g + 1) & (NGRP - 1);
                slot = atomicAdd(bcur + g * NB + b, 1);
            }
            if (slot < SEGCAP)
                bins[(size_t)(g * NB + b) * SEGCAP + slot] =
                    ((unsigned)(s & (BNODES - 1)) << 17) | (unsigned)d;
        }
    } else {
        // ---- prep part: nd[n]={x,y,z,hsum}; out coords ----
        int node = ((blockIdx.x - BINB) << 2) + (threadIdx.x >> 6);
        int lane = threadIdx.x & 63;
        if (node >= N) return;
        const float* row = features + (size_t)node * ROWF;
        float f0 = __builtin_nontemporal_load(row + lane);       // 0..63
        float f1 = (lane < ROWF - 64)
                 ? __builtin_nontemporal_load(row + 64 + lane) : 0.0f; // 64..66
        float v = (lane >= DIMV ? f0 : 0.0f) + f1;               // h = 3..66
        for (int off = 32; off > 0; off >>= 1) v += __shfl_xor(v, off, 64);
        float c0 = __shfl(f0, 0, 64);
        float c1 = __shfl(f0, 1, 64);
        float c2 = __shfl(f0, 2, 64);
        if (lane == 0) nd[node] = make_float4(c0, c1, c2, v);
        if (lane < DIMV) out[(size_t)node * ROWO + lane] = f0;
    }
}

// ---------- old prep (CSR/fallback paths only) ----------
__global__ void prep_kernel(const float* __restrict__ features,
                            float4* __restrict__ nd,
                            int* __restrict__ counts,
                            int* __restrict__ bcur, int nbc,
                            float* __restrict__ out, int N) {
    int gid = blockIdx.x * blockDim.x + threadIdx.x;
    if (gid < N) counts[gid] = 0;
    if (gid < nbc) bcur[gid] = 0;
    int node = gid >> 6;
    int lane = threadIdx.x & 63;
    if (node >= N) return;
    const float* row = features + (size_t)node * ROWF;
    float f0 = row[lane];
    float f1 = (lane < ROWF - 64) ? row[64 + lane] : 0.0f;
    float v = (lane >= DIMV ? f0 : 0.0f) + f1;
    for (int off = 32; off > 0; off >>= 1) v += __shfl_xor(v, off, 64);
    float c0 = __shfl(f0, 0, 64);
    float c1 = __shfl(f0, 1, 64);
    float c2 = __shfl(f0, 2, 64);
    if (lane == 0) nd[node] = make_float4(c0, c1, c2, v);
    if (lane < DIMV) out[(size_t)node * ROWO + lane] = f0;
}

// ---------- phase 2: fused 32-node bucket kernel, barrier-free compute ----------
// Edge build into LDS (one barrier), then each lane owns 4 (cluster,node) pairs:
// mu/sig loaded DIRECTLY global->reg via dwordx3 (lanes (h,n) cover two dense
// 384B segments per instruction), one k-loop computes 4 clusters per ue read.
// No mu/sig LDS, no per-chunk barriers. ~25.8KB LDS -> 6 blocks/CU.
__global__ __launch_bounds__(256, 6)
void fused_bucket_kernel(const int* __restrict__ bcur,
                         const unsigned int* __restrict__ bins,
                         const float4* __restrict__ nd,
                         const float* __restrict__ wd,
                         const float* __restrict__ bd,
                         const float* __restrict__ mu,
                         const float* __restrict__ sig,
                         float* __restrict__ out, int N, int NB) {
    __shared__ float4 ue[BNODES * PADSTR];     // 25.1 KB
    __shared__ float4 snd[BNODES];             // 512 B
    __shared__ int lcnt[BNODES];               // 128 B
    __shared__ int soff[NGRP + 1];
    int b = blockIdx.x;
    int base = b << BSH;
    int nn = N - base; if (nn > BNODES) nn = BNODES;
    int t = threadIdx.x;
    if (t < BNODES) {
        lcnt[t] = 0;
        snd[t] = (t < nn) ? nd[base + t] : make_float4(0.f, 0.f, 0.f, 0.f);
    }
    if (t < NGRP) {
        int c = bcur[t * NB + b];
        soff[t + 1] = (c > SEGCAP) ? SEGCAP : c;
    }
    if (t == 0) soff[0] = 0;
    __syncthreads();
    if (t == 0) {
#pragma unroll
        for (int g = 0; g < NGRP; ++g) soff[g + 1] += soff[g];
    }
    __syncthreads();
    {
        float w0 = wd[0], w1 = wd[1], w2 = wd[2];
        float w3 = wd[3], w4 = wd[4], w5 = wd[5];
        float w6 = wd[6], w7 = wd[7], w8 = wd[8];
        float b0 = bd[0], b1 = bd[1], b2 = bd[2];
        int total = soff[NGRP];
        for (int r = t; r < total; r += 256) {
            int g = 0;
#pragma unroll
            for (int gg = 1; gg < NGRP; ++gg) if (r >= soff[gg]) g = gg;
            int i = r - soff[g];
            unsigned p = bins[(size_t)(g * NB + b) * SEGCAP + i];
            int sl = p >> 17;
            int d  = p & 0x1FFFF;
            float4 pd = nd[d];                 // random gather, 1.6MB L2-resident
            int k = atomicAdd(&lcnt[sl], 1);
            if (k >= CAP) k = CAP - 1;         // never expected; OOB guard only
            float4 ps = snd[sl];
            float dx = pd.x - ps.x, dy = pd.y - ps.y, dz = pd.z - ps.z;
            float u0 = fast_tanh(dx * w0 + dy * w3 + dz * w6 + b0);
            float u1 = fast_tanh(dx * w1 + dy * w4 + dz * w7 + b1);
            float u2 = fast_tanh(dx * w2 + dy * w5 + dz * w8 + b2);
            // column swizzle k^((sl>>3)&3): de-aliases the 4-way bank groups
            // of the 32-row read pattern below (stride 49*4 dwords ≡ 4 mod 32)
            ue[sl * PADSTR + (k ^ ((sl >> 3) & 3))] = make_float4(u0, u1, u2, pd.w);
        }
    }
    __syncthreads();
    // ---- barrier-free compute: lane (wv,h,n) owns clusters {8wv+2j+h} ----
    int wv = t >> 6;
    int l  = t & 63;
    int h  = l >> 5;
    int n  = l & 31;
    size_t slab = (size_t)N * RV;
    int nid = base + ((n < nn) ? n : 0);
    float3 mv[4], sv[4];
#pragma unroll
    for (int j = 0; j < 4; ++j) {
        int c = 8 * wv + 2 * j + h;
        const float* mp = mu  + (size_t)c * slab + (size_t)nid * RV;
        const float* sp = sig + (size_t)c * slab + (size_t)nid * RV;
        mv[j] = *(const float3*)mp;            // dwordx3, dense 2x384B/instr
        sv[j] = *(const float3*)sp;
    }
    float mm[4][3], im[4][3], acc[4];
#pragma unroll
    for (int j = 0; j < 4; ++j) {
        mm[j][0] = mv[j].x; mm[j][1] = mv[j].y; mm[j][2] = mv[j].z;
        im[j][0] = __builtin_amdgcn_rcpf(sv[j].x);
        im[j][1] = __builtin_amdgcn_rcpf(sv[j].y);
        im[j][2] = __builtin_amdgcn_rcpf(sv[j].z);
        acc[j] = 0.0f;
    }
    int cnt = (n < nn) ? min(lcnt[n], CAP) : 0;
    int key = (n >> 3) & 3;
    for (int k = 0; k < cnt; ++k) {
        float4 q = ue[n * PADSTR + (k ^ key)];
#pragma unroll
        for (int j = 0; j < 4; ++j) {
            float d0 = q.x - mm[j][0], d1 = q.y - mm[j][1], d2 = q.z - mm[j][2];
            float t2 = d0 * d0 * im[j][0] + d1 * d1 * im[j][1] + d2 * d2 * im[j][2];
            acc[j] += __expf(-0.5f * t2) * q.w;
        }
    }
    if (n < nn) {
        float* orow = out + (size_t)(base + n) * ROWO + DIMV;
#pragma unroll
        for (int j = 0; j < 4; ++j) orow[8 * wv + 2 * j + h] = acc[j];
    }
}

// ---------- full path (exact CSR + scan), ws fallback ----------

__global__ void hist_kernel(const int2* __restrict__ ei2, int* __restrict__ counts, int E) {
    int e = blockIdx.x * blockDim.x + threadIdx.x;
    if (e >= E) return;
    atomicAdd(counts + ei2[e].x, 1);
}

__global__ void scan_a_kernel(const int* __restrict__ counts, int* __restrict__ offsets,
                              int* __restrict__ partials, int N) {
    __shared__ int sm[SCAN_T];
    int t = threadIdx.x;
    int i = blockIdx.x * SCAN_T + t;
    int c = (i < N) ? counts[i] : 0;
    sm[t] = c;
    __syncthreads();
    for (int off = 1; off < SCAN_T; off <<= 1) {
        int v = (t >= off) ? sm[t - off] : 0;
        __syncthreads();
        sm[t] += v;
        __syncthreads();
    }
    if (i < N) offsets[i] = sm[t] - c;
    if (t == SCAN_T - 1) partials[blockIdx.x] = sm[t];
}

__global__ void scan_b_kernel(int* __restrict__ partials, int B) {
    __shared__ int sm[SCAN_T];
    int t = threadIdx.x;
    int c = (t < B) ? partials[t] : 0;
    sm[t] = c;
    __syncthreads();
    for (int off = 1; off < SCAN_T; off <<= 1) {
        int v = (t >= off) ? sm[t - off] : 0;
        __syncthreads();
        sm[t] += v;
        __syncthreads();
    }
    if (t < B) partials[t] = sm[t] - c;
}

__global__ void scan_c_kernel(int* __restrict__ offsets, const int* __restrict__ partials,
                              int* __restrict__ cursor, int N, int E) {
    int i = blockIdx.x * blockDim.x + threadIdx.x;
    if (i == 0) offsets[N] = E;
    if (i >= N) return;
    int off = offsets[i] + partials[i / SCAN_T];
    offsets[i] = off;
    cursor[i] = off;
}

__global__ void scatter_u_kernel(const int2* __restrict__ ei2, int* __restrict__ cursor,
                                 const float4* __restrict__ nd,
                                 const float* __restrict__ wd, const float* __restrict__ bd,
                                 float4* __restrict__ ue, int E) {
    int e = blockIdx.x * blockDim.x + threadIdx.x;
    if (e >= E) return;
    int2 sd = ei2[e];
    int pos = atomicAdd(cursor + sd.x, 1);
    float4 ps = nd[sd.x];
    float4 pd = nd[sd.y];
    float dx = pd.x - ps.x, dy = pd.y - ps.y, dz = pd.z - ps.z;
    float u0 = fast_tanh(dx * wd[0] + dy * wd[3] + dz * wd[6] + bd[0]);
    float u1 = fast_tanh(dx * wd[1] + dy * wd[4] + dz * wd[7] + bd[1]);
    float u2 = fast_tanh(dx * wd[2] + dy * wd[5] + dz * wd[8] + bd[2]);
    ue[pos] = make_float4(u0, u1, u2, pd.w);
}

__global__ void node_acc2_kernel(const int* __restrict__ offsets,
                                 const float4* __restrict__ ue,
                                 const float* __restrict__ mu,
                                 const float* __restrict__ sig,
                                 float* __restrict__ out, int N) {
    int node = (blockIdx.x * blockDim.x + threadIdx.x) >> 6;
    if (node >= N) return;
    int lane = threadIdx.x & 63;
    int c = lane & 31;
    int half = lane >> 5;
    size_t slab = (size_t)N * RV;
    const float* mp = mu + (size_t)c * slab + (size_t)node * RV;
    const float* sp = sig + (size_t)c * slab + (size_t)node * RV;
    float m0 = mp[0], m1 = mp[1], m2 = mp[2];
    float i0 = __builtin_amdgcn_rcpf(sp[0]);
    float i1 = __builtin_amdgcn_rcpf(sp[1]);
    float i2 = __builtin_amdgcn_rcpf(sp[2]);
    int off0 = offsets[node], off1 = offsets[node + 1];
    float acc = 0.0f;
    for (int i = off0 + half; i < off1; i += 2) {
        float4 q = ue[i];
        float d0 = q.x - m0, d1 = q.y - m1, d2 = q.z - m2;
        float t = d0 * d0 * i0 + d1 * d1 * i1 + d2 * d2 * i2;
        acc += __expf(-0.5f * t) * q.w;
    }
    acc += __shfl_xor(acc, 32, 64);
    if (half == 0) out[(size_t)node * ROWO + DIMV + c] = acc;
}

// ---------- last-resort path (edge-atomic) ----------

__global__ void fb_pre_kernel(const float* __restrict__ features,
                              float4* __restrict__ nd, float* __restrict__ out, int N) {
    int gid = blockIdx.x * blockDim.x + threadIdx.x;
    int node = gid >> 6;
    int lane = threadIdx.x & 63;
    if (node >= N) return;
    const float* row = features + (size_t)node * ROWF;
    float f0 = row[lane];
    float f1 = (lane < ROWF - 64) ? row[64 + lane] : 0.0f;
    float v = (lane >= DIMV ? f0 : 0.0f) + f1;
    for (int off = 32; off > 0; off >>= 1) v += __shfl_xor(v, off, 64);
    float c0 = __shfl(f0, 0, 64);
    float c1 = __shfl(f0, 1, 64);
    float c2 = __shfl(f0, 2, 64);
    if (lane == 0) nd[node] = make_float4(c0, c1, c2, v);
    float* orow = out + (size_t)node * ROWO;
    if (lane < DIMV) orow[lane] = f0;
    else if (lane < ROWO) orow[lane] = 0.0f;
}

__global__ void fb_edge_kernel(const int* __restrict__ ei, const float4* __restrict__ nd,
                               const float* __restrict__ wd, const float* __restrict__ bd,
                               const float* __restrict__ mu, const float* __restrict__ sig,
                               float* __restrict__ out, int N, int E) {
    int e = blockIdx.x * blockDim.x + threadIdx.x;
    if (e >= E) return;
    int s = ei[2 * e];
    int d = ei[2 * e + 1];
    float4 ps = nd[s];
    float4 pd = nd[d];
    float dx = pd.x - ps.x, dy = pd.y - ps.y, dz = pd.z - ps.z;
    float u0 = fast_tanh(dx * wd[0] + dy * wd[3] + dz * wd[6] + bd[0]);
    float u1 = fast_tanh(dx * wd[1] + dy * wd[4] + dz * wd[7] + bd[1]);
    float u2 = fast_tanh(dx * wd[2] + dy * wd[5] + dz * wd[8] + bd[2]);
    float hs = pd.w;
    float* oagg = out + (size_t)s * ROWO + DIMV;
    size_t nodeoff = (size_t)s * RV;
    size_t slab = (size_t)N * RV;
#pragma unroll 4
    for (int c = 0; c < CV; ++c) {
        const float* mp = mu + (size_t)c * slab + nodeoff;
        const float* sp = sig + (size_t)c * slab + nodeoff;
        float d0 = u0 - mp[0], d1 = u1 - mp[1], d2 = u2 - mp[2];
        float t = d0 * d0 * __builtin_amdgcn_rcpf(sp[0])
                + d1 * d1 * __builtin_amdgcn_rcpf(sp[1])
                + d2 * d2 * __builtin_amdgcn_rcpf(sp[2]);
        atomicAdd(oagg + c, __expf(-0.5f * t) * hs);
    }
}

extern "C" void kernel_launch(void* const* d_in, const int* in_sizes, int n_in,
                              void* d_out, int out_size, void* d_ws, size_t ws_size,
                              hipStream_t stream) {
    const float* features = (const float*)d_in[0];
    const int*   ei       = (const int*)d_in[1];
    const int2*  ei2      = (const int2*)d_in[1];
    const float* wd       = (const float*)d_in[2];
    const float* bd       = (const float*)d_in[3];
    const float* mu       = (const float*)d_in[4];
    const float* sig      = (const float*)d_in[5];
    float* out = (float*)d_out;

    int N = in_sizes[0] / ROWF;
    int E = in_sizes[1] / 2;
    int B = (N + SCAN_T - 1) / SCAN_T;
    int NB = (N + BNODES - 1) / BNODES;
    int PB = (N + 3) / 4;                       // prep blocks in merged kernel

    size_t cur = 0;
    auto take = [&](size_t bytes) { size_t p = cur; cur += (bytes + 255) & ~(size_t)255; return p; };
    size_t o_nd      = take((size_t)N * sizeof(float4));
    size_t o_counts  = take((size_t)N * sizeof(int));
    size_t o_offsets = take((size_t)(N + 1) * sizeof(int));
    size_t o_cursor  = take((size_t)N * sizeof(int));
    size_t o_part    = take((size_t)SCAN_T * sizeof(int));
    size_t o_bcur    = take((size_t)NGRP * NB * sizeof(int));
    size_t o_bins    = take((size_t)NGRP * NB * SEGCAP * sizeof(unsigned int));
    size_t o_tail    = cur;     // CSR ue only
    size_t need_fused = o_tail; // fused path needs nothing past bins
    size_t need_full  = o_tail + (((size_t)E * sizeof(float4) + 255) & ~(size_t)255);

    char* ws = (char*)d_ws;
    float4* nd   = (float4*)(ws + o_nd);
    int* counts  = (int*)(ws + o_counts);
    int* offsets = (int*)(ws + o_offsets);
    int* cursor  = (int*)(ws + o_cursor);
    int* part    = (int*)(ws + o_part);
    int* bcur    = (int*)(ws + o_bcur);
    unsigned int* bins = (unsigned int*)(ws + o_bins);

    if (ws_size >= need_fused && N < (1 << 17)) {
        // 3-kernel path: zero cursors -> (prep ∥ bin) merged -> fused buckets
        zero_kernel<<<(NGRP * NB + 255) / 256, 256, 0, stream>>>(bcur, NGRP * NB);
        prep_bin_kernel<<<BINB + PB, 256, 0, stream>>>(features, nd, out, ei2, bcur, bins, N, E, NB);
        fused_bucket_kernel<<<NB, 256, 0, stream>>>(bcur, bins, nd, wd, bd, mu, sig, out, N, NB);
    } else if (ws_size >= need_full && B <= SCAN_T) {
        float4* ue = (float4*)(ws + o_tail);
        prep_kernel<<<(N + 3) / 4, 256, 0, stream>>>(features, nd, counts, bcur, 0, out, N);
        hist_kernel<<<(E + 255) / 256, 256, 0, stream>>>(ei2, counts, E);
        scan_a_kernel<<<B, SCAN_T, 0, stream>>>(counts, offsets, part, N);
        scan_b_kernel<<<1, SCAN_T, 0, stream>>>(part, B);
        scan_c_kernel<<<(N + 255) / 256, 256, 0, stream>>>(offsets, part, cursor, N, E);
        scatter_u_kernel<<<(E + 255) / 256, 256, 0, stream>>>(ei2, cursor, nd, wd, bd, ue, E);
        node_acc2_kernel<<<(N + 3) / 4, 256, 0, stream>>>(offsets, ue, mu, sig, out, N);
    } else {
        fb_pre_kernel<<<(N + 3) / 4, 256, 0, stream>>>(features, nd, out, N);
        fb_edge_kernel<<<(E + 255) / 256, 256, 0, stream>>>(ei, nd, wd, bd, mu, sig, out, N, E);
    }
}